// Round 2
// baseline (198.269 us; speedup 1.0000x reference)
//
#include <hip/hip_runtime.h>

// DiffKS: x = invert_lpc(y, A_exc)  [order-6 time-varying FIR]
//         out = sample_wise_lpc(x, A_loop)  [order-2 time-varying IIR]
// B=48, T=88200, fp32.
//
// R5: wave-count reduction. R4 falsified the transaction theory (4x fewer
// line-touches, identical 60 us); Little's law on the counters gives a
// ~12 us average wave lifetime vs ~0.2 us of VALU work -> duration is
// dominated by per-wave/per-WG fixed overhead. So: 8 samples/lane
// (OUT_W=480), waves 18912->8832, workgroups 4728->1104 (WPB=8, legal
// since there is no LDS and no barrier).
//  - Direct per-lane loads (R3 style, no LDS): R4 proved this transaction
//    level non-binding at equal per-CU pressure.
//  - y history (6 taps) via 8 __shfl_up of the lane's two float4s
//    (lane 0 loads its halo directly, guarded).
//  - Warm-up still 32 samples (lanes 0..3): truncation ~0.5^16*|y|.
//  - Wave scan: d=1,2 FULL (2x2+vec), d=4 c-only -> covers 8 lanes =
//    64 samples, P spans 32 steps (norm <=1.5e-5) at the c-only round:
//    IDENTICAL error structure to R3/R4 (which measured absmax 2^-7).
//    24 shuffles total (vs 30 for half the work in R3).
//  - Per-lane guard t0 in [0,T) (both multiples of 8) covers chunk-0
//    zero-state, cross-row isolation, and the ragged last chunk.

#define T_LEN 88200
#define B_N   48
#define SPL   8            // samples per lane
#define OUT_W 480          // output samples per wave (512 - WUP)
#define WUP   32           // warm-up samples (lanes 0..3)
#define NCH   184          // ceil(T_LEN / OUT_W)
#define WPB   8            // waves per block (block = 512)
#define NWAVES (B_N * NCH) // 8832

__device__ __forceinline__ float4 zero4() { return make_float4(0.f, 0.f, 0.f, 0.f); }

__device__ __forceinline__ float4 ld_guard(const float* p, int t) {
    // callers guarantee t % 4 == 0
    if (t >= 0 && t + 3 < T_LEN) return *(const float4*)(p + t);
    return zero4();
}

__global__ __launch_bounds__(512, 4) void diffks_kernel(
    const float* __restrict__ y, const float* __restrict__ A_exc,
    const float* __restrict__ A_loop, float* __restrict__ out) {
    const int tid  = threadIdx.x;
    const int widx = tid >> 6;
    const int lane = tid & 63;
    const int w = blockIdx.x * WPB + widx;      // 0..8831 (grid exact)
    const int b = w / NCH;
    const int c = w - b * NCH;
    const int s  = c * OUT_W;
    const int w0 = s - WUP;
    const int t0 = w0 + SPL * lane;             // this lane's first sample

    const float* yb  = y      + (size_t)b * T_LEN;
    const float* aeb = A_exc  + (size_t)b * T_LEN * 6;
    const float* alb = A_loop + (size_t)b * T_LEN * 2;
    float*       ob  = out    + (size_t)b * T_LEN;

    // ---- per-lane direct loads (t0 % 8 == 0, T_LEN % 8 == 0 -> whole-lane
    //      guard; all pointers 16B-aligned) ----
    const bool valid = (t0 >= 0) && (t0 < T_LEN);
    float4 yv0, yv1, ae[12], al[4];
    if (valid) {
        yv0 = *(const float4*)(yb + t0);
        yv1 = *(const float4*)(yb + t0 + 4);
        const float4* pae = (const float4*)(aeb + (size_t)t0 * 6);
#pragma unroll
        for (int k = 0; k < 12; ++k) ae[k] = pae[k];
        const float4* pal = (const float4*)(alb + (size_t)t0 * 2);
#pragma unroll
        for (int k = 0; k < 4; ++k) al[k] = pal[k];
    } else {
        yv0 = yv1 = zero4();
#pragma unroll
        for (int k = 0; k < 12; ++k) ae[k] = zero4();
#pragma unroll
        for (int k = 0; k < 4; ++k) al[k] = zero4();
    }

    // ---- y history via shuffles (lane 0 loads halo) ----
    float4 pv0, pv1;
    pv0.x = __shfl_up(yv0.x, 1, 64); pv0.y = __shfl_up(yv0.y, 1, 64);
    pv0.z = __shfl_up(yv0.z, 1, 64); pv0.w = __shfl_up(yv0.w, 1, 64);
    pv1.x = __shfl_up(yv1.x, 1, 64); pv1.y = __shfl_up(yv1.y, 1, 64);
    pv1.z = __shfl_up(yv1.z, 1, 64); pv1.w = __shfl_up(yv1.w, 1, 64);
    if (lane == 0) {
        pv0 = ld_guard(yb, t0 - 8);
        pv1 = ld_guard(yb, t0 - 4);
    }

    float yw[16] = { pv0.x, pv0.y, pv0.z, pv0.w, pv1.x, pv1.y, pv1.z, pv1.w,
                     yv0.x, yv0.y, yv0.z, yv0.w, yv1.x, yv1.y, yv1.z, yv1.w };
    float aef[48] = {
        ae[0].x, ae[0].y, ae[0].z, ae[0].w, ae[1].x, ae[1].y, ae[1].z, ae[1].w,
        ae[2].x, ae[2].y, ae[2].z, ae[2].w, ae[3].x, ae[3].y, ae[3].z, ae[3].w,
        ae[4].x, ae[4].y, ae[4].z, ae[4].w, ae[5].x, ae[5].y, ae[5].z, ae[5].w,
        ae[6].x, ae[6].y, ae[6].z, ae[6].w, ae[7].x, ae[7].y, ae[7].z, ae[7].w,
        ae[8].x, ae[8].y, ae[8].z, ae[8].w, ae[9].x, ae[9].y, ae[9].z, ae[9].w,
        ae[10].x, ae[10].y, ae[10].z, ae[10].w, ae[11].x, ae[11].y, ae[11].z, ae[11].w };
    float alf[16] = { al[0].x, al[0].y, al[0].z, al[0].w,
                      al[1].x, al[1].y, al[1].z, al[1].w,
                      al[2].x, al[2].y, al[2].z, al[2].w,
                      al[3].x, al[3].y, al[3].z, al[3].w };

    // ---- FIR + local affine composition over 8 samples ----
    float xs[SPL];
    float p00 = 1.f, p01 = 0.f, p10 = 0.f, p11 = 1.f, c0 = 0.f, c1 = 0.f;
#pragma unroll
    for (int j = 0; j < SPL; ++j) {
        float xv = yw[8 + j];
#pragma unroll
        for (int k = 1; k <= 6; ++k)
            xv = fmaf(aef[j * 6 + (k - 1)], yw[8 + j - k], xv);
        xs[j] = xv;
        const float a1 = alf[2 * j], a2 = alf[2 * j + 1];
        // P <- M_t * P ; c <- M_t * c + b_t   (M_t = [[-a1,-a2],[1,0]])
        const float n00 = fmaf(-a1, p00, -a2 * p10);
        const float n01 = fmaf(-a1, p01, -a2 * p11);
        p10 = p00; p11 = p01; p00 = n00; p01 = n01;
        const float nc0 = fmaf(-a1, c0, fmaf(-a2, c1, xv));
        c1 = c0; c0 = nc0;
    }

    // ---- truncated wave scan: d=1,2 full; d=4 c-only ----
#pragma unroll
    for (int d = 1; d <= 2; d <<= 1) {
        const float q00 = __shfl_up(p00, d, 64), q01 = __shfl_up(p01, d, 64);
        const float q10 = __shfl_up(p10, d, 64), q11 = __shfl_up(p11, d, 64);
        const float qc0 = __shfl_up(c0, d, 64),  qc1 = __shfl_up(c1, d, 64);
        if (lane >= d) {
            const float m00 = fmaf(p00, q00, p01 * q10);
            const float m01 = fmaf(p00, q01, p01 * q11);
            const float m10 = fmaf(p10, q00, p11 * q10);
            const float m11 = fmaf(p10, q01, p11 * q11);
            const float nc0 = fmaf(p00, qc0, fmaf(p01, qc1, c0));
            const float nc1 = fmaf(p10, qc0, fmaf(p11, qc1, c1));
            p00 = m00; p01 = m01; p10 = m10; p11 = m11; c0 = nc0; c1 = nc1;
        }
    }
    {   // d = 4: P spans 32 steps (norm <=1.5e-5) -> only c matters
        const float qc0 = __shfl_up(c0, 4, 64), qc1 = __shfl_up(c1, 4, 64);
        if (lane >= 4) {
            const float nc0 = fmaf(p00, qc0, fmaf(p01, qc1, c0));
            const float nc1 = fmaf(p10, qc0, fmaf(p11, qc1, c1));
            c0 = nc0; c1 = nc1;
        }
    }

    // ---- exclusive prefix = incoming state; replay 8 samples ----
    float y1 = __shfl_up(c0, 1, 64);
    float y2 = __shfl_up(c1, 1, 64);
    if (lane == 0) { y1 = 0.f; y2 = 0.f; }
#pragma unroll
    for (int j = 0; j < SPL; ++j) {
        const float yt = fmaf(-alf[2 * j], y1, fmaf(-alf[2 * j + 1], y2, xs[j]));
        y2 = y1; y1 = yt;
        xs[j] = yt;           // reuse xs as output buffer (saves 8 VGPRs)
    }

    // ---- direct coalesced stores (lanes 4..63 = output region) ----
    if (lane >= 4 && t0 < T_LEN) {
        *(float4*)(ob + t0)     = make_float4(xs[0], xs[1], xs[2], xs[3]);
        *(float4*)(ob + t0 + 4) = make_float4(xs[4], xs[5], xs[6], xs[7]);
    }
}

extern "C" void kernel_launch(void* const* d_in, const int* in_sizes, int n_in,
                              void* d_out, int out_size, void* d_ws, size_t ws_size,
                              hipStream_t stream) {
    const float* y      = (const float*)d_in[0];
    const float* A_exc  = (const float*)d_in[1];
    const float* A_loop = (const float*)d_in[2];
    float* out = (float*)d_out;

    const int grid = NWAVES / WPB;        // 1104 blocks of 8 waves
    diffks_kernel<<<grid, 512, 0, stream>>>(y, A_exc, A_loop, out);
}

// Round 3
// 191.232 us; speedup vs baseline: 1.0368x; 1.0368x over previous
//
#include <hip/hip_runtime.h>

// DiffKS: x = invert_lpc(y, A_exc)  [order-6 time-varying FIR]
//         out = sample_wise_lpc(x, A_loop)  [order-2 time-varying IIR]
// B=48, T=88200, fp32.
//
// R6: persistent-wave software pipeline. R3/R4/R5 all pinned at 60-70 us
// moving ~163 MB (~2.5 TB/s chip read rate, 10.5 GB/s/CU) with every pipe
// <10% busy and duration invariant to pattern/residency/wave-count.
// Surviving theory: burst-then-starve MLP -- each wave issues one load
// burst, waits once, computes, dies; per-CU outstanding bytes average is
// far below what latency*BW requires. Fix: 1024 persistent waves, each
// iterating ~9 chunks with DOUBLE-BUFFERED LDS staging of A_exc/A_loop via
// global_load_lds width-16 and a counted s_waitcnt vmcnt(16) (never 0 in
// steady state): the next chunk's 16 KB is ALWAYS in flight while the
// current chunk computes.
//  - Block = 1 wave (64 thr), LDS 32 KB/block -> 5 resident/CU possible,
//    grid 1024 -> ~4/CU. Deliberate TLP->ILP trade.
//  - y stays direct per-lane (32 B lane stride, 2 lanes/line) + shuffles.
//  - Chunk geometry identical to R5 (SPL=8, OUT_W=480, WUP=32, truncated
//    scan d=1,2 full + d=4 c-only) -> identical numerics (absmax 2^-7).
//  - Edge chunks k=0 (reads before A_exc base) and k=NCHUNKS-1 (reads past
//    allocation end) take the guarded direct register path, never staged.
//  - Staged windows crossing ROW boundaries (c==0 / c==183 interior) read
//    neighbor-row garbage that is consumed only by lanes whose y inputs
//    are zeroed / whose stores are guarded -> harmless, finite (|a|<=.25).

#define T_LEN 88200
#define B_N   48
#define SPL   8            // samples per lane
#define OUT_W 480          // output samples per wave-chunk
#define WUP   32           // warm-up samples (lanes 0..3)
#define NCH   184          // chunks per batch row
#define NCHUNKS (B_N * NCH)   // 8832
#define NPW   1024         // persistent waves (= blocks of 64)
#define AE_F  3072         // A_exc floats per chunk window (512*6)
#define AL_F  1024         // A_loop floats per chunk window (512*2)

__device__ __forceinline__ float4 zero4() { return make_float4(0.f, 0.f, 0.f, 0.f); }

__device__ __forceinline__ float4 ld_guard(const float* p, int t) {
    // callers guarantee t % 4 == 0
    if (t >= 0 && t + 3 < T_LEN) return *(const float4*)(p + t);
    return zero4();
}

__device__ __forceinline__ void gload_lds16(const float* g, float* l) {
    __builtin_amdgcn_global_load_lds(
        (const __attribute__((address_space(1))) unsigned int*)g,
        (__attribute__((address_space(3))) unsigned int*)l, 16, 0, 0);
}

__global__ __launch_bounds__(64) void diffks_kernel(
    const float* __restrict__ y, const float* __restrict__ A_exc,
    const float* __restrict__ A_loop, float* __restrict__ out) {
    __shared__ float sae[2][AE_F];   // 24 KB
    __shared__ float sal[2][AL_F];   //  8 KB
    const int lane = threadIdx.x;    // block = exactly one wave
    const int g    = blockIdx.x;     // 0..NPW-1

    // ---- prologue: stage first chunk (g>=1 is always interior) ----
    if (g != 0) {
        const int b = g / NCH, c = g - b * NCH;
        const ptrdiff_t w0 = (ptrdiff_t)c * OUT_W - WUP;
        const float* ga = A_exc + ((ptrdiff_t)b * T_LEN + w0) * 6 + lane * 4;
        const float* gl = A_loop + ((ptrdiff_t)b * T_LEN + w0) * 2 + lane * 4;
#pragma unroll
        for (int j = 0; j < 12; ++j) gload_lds16(ga + j * 256, &sae[0][j * 256]);
#pragma unroll
        for (int j = 0; j < 4; ++j)  gload_lds16(gl + j * 256, &sal[0][j * 256]);
    }

    int s = 0;
    for (int k = g; k < NCHUNKS; k += NPW, s ^= 1) {
        const int b  = k / NCH, c = k - b * NCH;
        const int w0 = c * OUT_W - WUP;
        const int t0 = w0 + SPL * lane;
        const float* yb = y   + (size_t)b * T_LEN;
        float*       ob = out + (size_t)b * T_LEN;

        // ---- y direct loads (issued first: drained by the counted wait) ----
        const bool valid = (t0 >= 0) && (t0 < T_LEN);
        float4 yv0, yv1;
        if (valid) {
            yv0 = *(const float4*)(yb + t0);
            yv1 = *(const float4*)(yb + t0 + 4);
        } else { yv0 = yv1 = zero4(); }
        float4 h0 = zero4(), h1 = zero4();
        if (lane == 0) {                       // halo (divergent, 1 lane)
            h0 = ld_guard(yb, t0 - 8);
            h1 = ld_guard(yb, t0 - 4);
        }

        // ---- issue NEXT chunk's stage into the other buffer ----
        const int  kn = k + NPW;
        const bool next_int = (kn < NCHUNKS - 1);   // kn >= NPW, never 0
        if (next_int) {
            const int bn = kn / NCH, cn = kn - bn * NCH;
            const ptrdiff_t wn = (ptrdiff_t)cn * OUT_W - WUP;
            const float* ga = A_exc + ((ptrdiff_t)bn * T_LEN + wn) * 6 + lane * 4;
            const float* gl = A_loop + ((ptrdiff_t)bn * T_LEN + wn) * 2 + lane * 4;
            float* la = &sae[s ^ 1][0];
            float* ll = &sal[s ^ 1][0];
#pragma unroll
            for (int j = 0; j < 12; ++j) gload_lds16(ga + j * 256, la + j * 256);
#pragma unroll
            for (int j = 0; j < 4; ++j)  gload_lds16(gl + j * 256, ll + j * 256);
        }

        // ---- obtain current coefficients ----
        float4 ae[12], al4[4];
        const bool cur_int = (k != 0) && (k != NCHUNKS - 1);
        if (cur_int) {
            // counted wait: leave the 16 next-stage loads in flight
            if (next_int) asm volatile("s_waitcnt vmcnt(16)" ::: "memory");
            else          asm volatile("s_waitcnt vmcnt(0)"  ::: "memory");
            const float4* pa = (const float4*)&sae[s][48 * lane];
            const float4* pl = (const float4*)&sal[s][16 * lane];
#pragma unroll
            for (int j = 0; j < 12; ++j) ae[j] = pa[j];
#pragma unroll
            for (int j = 0; j < 4; ++j)  al4[j] = pl[j];
        } else {
            if (valid) {
                const float4* pa = (const float4*)(A_exc + ((size_t)b * T_LEN + t0) * 6);
                const float4* pl = (const float4*)(A_loop + ((size_t)b * T_LEN + t0) * 2);
#pragma unroll
                for (int j = 0; j < 12; ++j) ae[j] = pa[j];
#pragma unroll
                for (int j = 0; j < 4; ++j)  al4[j] = pl[j];
            } else {
#pragma unroll
                for (int j = 0; j < 12; ++j) ae[j] = zero4();
#pragma unroll
                for (int j = 0; j < 4; ++j)  al4[j] = zero4();
            }
        }

        // ---- y history via shuffles (lane 0 halo from h0/h1) ----
        float4 pv0, pv1;
        pv0.x = __shfl_up(yv0.x, 1, 64); pv0.y = __shfl_up(yv0.y, 1, 64);
        pv0.z = __shfl_up(yv0.z, 1, 64); pv0.w = __shfl_up(yv0.w, 1, 64);
        pv1.x = __shfl_up(yv1.x, 1, 64); pv1.y = __shfl_up(yv1.y, 1, 64);
        pv1.z = __shfl_up(yv1.z, 1, 64); pv1.w = __shfl_up(yv1.w, 1, 64);
        if (lane == 0) { pv0 = h0; pv1 = h1; }

        float yw[16] = { pv0.x, pv0.y, pv0.z, pv0.w, pv1.x, pv1.y, pv1.z, pv1.w,
                         yv0.x, yv0.y, yv0.z, yv0.w, yv1.x, yv1.y, yv1.z, yv1.w };
        float aef[48] = {
            ae[0].x, ae[0].y, ae[0].z, ae[0].w, ae[1].x, ae[1].y, ae[1].z, ae[1].w,
            ae[2].x, ae[2].y, ae[2].z, ae[2].w, ae[3].x, ae[3].y, ae[3].z, ae[3].w,
            ae[4].x, ae[4].y, ae[4].z, ae[4].w, ae[5].x, ae[5].y, ae[5].z, ae[5].w,
            ae[6].x, ae[6].y, ae[6].z, ae[6].w, ae[7].x, ae[7].y, ae[7].z, ae[7].w,
            ae[8].x, ae[8].y, ae[8].z, ae[8].w, ae[9].x, ae[9].y, ae[9].z, ae[9].w,
            ae[10].x, ae[10].y, ae[10].z, ae[10].w,
            ae[11].x, ae[11].y, ae[11].z, ae[11].w };
        float alf[16] = { al4[0].x, al4[0].y, al4[0].z, al4[0].w,
                          al4[1].x, al4[1].y, al4[1].z, al4[1].w,
                          al4[2].x, al4[2].y, al4[2].z, al4[2].w,
                          al4[3].x, al4[3].y, al4[3].z, al4[3].w };

        // ---- FIR + local affine composition over 8 samples ----
        float xs[SPL];
        float p00 = 1.f, p01 = 0.f, p10 = 0.f, p11 = 1.f, c0 = 0.f, c1 = 0.f;
#pragma unroll
        for (int j = 0; j < SPL; ++j) {
            float xv = yw[8 + j];
#pragma unroll
            for (int kk = 1; kk <= 6; ++kk)
                xv = fmaf(aef[j * 6 + (kk - 1)], yw[8 + j - kk], xv);
            xs[j] = xv;
            const float a1 = alf[2 * j], a2 = alf[2 * j + 1];
            const float n00 = fmaf(-a1, p00, -a2 * p10);
            const float n01 = fmaf(-a1, p01, -a2 * p11);
            p10 = p00; p11 = p01; p00 = n00; p01 = n01;
            const float nc0 = fmaf(-a1, c0, fmaf(-a2, c1, xv));
            c1 = c0; c0 = nc0;
        }

        // ---- truncated wave scan: d=1,2 full; d=4 c-only ----
#pragma unroll
        for (int d = 1; d <= 2; d <<= 1) {
            const float q00 = __shfl_up(p00, d, 64), q01 = __shfl_up(p01, d, 64);
            const float q10 = __shfl_up(p10, d, 64), q11 = __shfl_up(p11, d, 64);
            const float qc0 = __shfl_up(c0, d, 64),  qc1 = __shfl_up(c1, d, 64);
            if (lane >= d) {
                const float m00 = fmaf(p00, q00, p01 * q10);
                const float m01 = fmaf(p00, q01, p01 * q11);
                const float m10 = fmaf(p10, q00, p11 * q10);
                const float m11 = fmaf(p10, q01, p11 * q11);
                const float nc0 = fmaf(p00, qc0, fmaf(p01, qc1, c0));
                const float nc1 = fmaf(p10, qc0, fmaf(p11, qc1, c1));
                p00 = m00; p01 = m01; p10 = m10; p11 = m11; c0 = nc0; c1 = nc1;
            }
        }
        {   // d = 4: P spans 32 steps (norm <=1.5e-5) -> only c matters
            const float qc0 = __shfl_up(c0, 4, 64), qc1 = __shfl_up(c1, 4, 64);
            if (lane >= 4) {
                const float nc0 = fmaf(p00, qc0, fmaf(p01, qc1, c0));
                const float nc1 = fmaf(p10, qc0, fmaf(p11, qc1, c1));
                c0 = nc0; c1 = nc1;
            }
        }

        // ---- exclusive prefix = incoming state; replay 8 samples ----
        float y1 = __shfl_up(c0, 1, 64);
        float y2 = __shfl_up(c1, 1, 64);
        if (lane == 0) { y1 = 0.f; y2 = 0.f; }
#pragma unroll
        for (int j = 0; j < SPL; ++j) {
            const float yt = fmaf(-alf[2 * j], y1, fmaf(-alf[2 * j + 1], y2, xs[j]));
            y2 = y1; y1 = yt;
            xs[j] = yt;
        }

        // ---- coalesced stores (lanes 4..63 = output region) ----
        if (lane >= 4 && t0 < T_LEN) {
            *(float4*)(ob + t0)     = make_float4(xs[0], xs[1], xs[2], xs[3]);
            *(float4*)(ob + t0 + 4) = make_float4(xs[4], xs[5], xs[6], xs[7]);
        }
    }
}

extern "C" void kernel_launch(void* const* d_in, const int* in_sizes, int n_in,
                              void* d_out, int out_size, void* d_ws, size_t ws_size,
                              hipStream_t stream) {
    const float* y      = (const float*)d_in[0];
    const float* A_exc  = (const float*)d_in[1];
    const float* A_loop = (const float*)d_in[2];
    float* out = (float*)d_out;

    diffks_kernel<<<NPW, 64, 0, stream>>>(y, A_exc, A_loop, out);
}

// Round 4
// 188.853 us; speedup vs baseline: 1.0499x; 1.0126x over previous
//
#include <hip/hip_runtime.h>

// DiffKS: x = invert_lpc(y, A_exc)  [order-6 time-varying FIR]
//         out = sample_wise_lpc(x, A_loop)  [order-2 time-varying IIR]
// B=48, T=88200, fp32.
//
// R7 = revert to R3 (measured best: 60.4 us/dispatch, 186.7 us JSON).
// Rationale: R4 (LDS-staged dense loads), R5 (2x fatter waves), and R6
// (persistent waves + double-buffered counted-vmcnt pipeline, ~64 KB/CU
// sustained in flight) all landed at 60-70 us moving the same ~163 MB.
// Duration is invariant to access pattern, wave count, occupancy, MLP,
// and data residency (L3-warm dispatch = identical time), with all pipes
// <10% busy. Effective read BW is pinned at ~2.6 TB/s across all
// structures -> the binding constraint is external to kernel structure
// (short-dispatch clock floor / uniform system cap). R3 is the best AND
// simplest point in the explored space; this round re-locks it and
// serves as the reproducibility check for the noise band (expect JSON
// 185-192 us). If confirmed, the session is at its operative ceiling.
//
// R3 design: LDS-free, one wave per 224-output-sample chunk.
//  - 4 samples/lane -> per-lane A_exc slice = 96 B (16B-aligned float4 x6),
//    A_loop slice = 32 B (float4 x2), y slice = 16 B: ALL direct global
//    loads, no LDS staging, no barrier.
//  - y history (6 taps) via 2x __shfl_up of the lane's float4 (lanes 0/1
//    load their halo directly, guarded).
//  - 32-sample zero-state warm-up (lanes 0..7). |a|<=0.25 -> companion
//    2-step contraction 0.5 -> truncation error ~0.5^16*|y| ~ 3e-4.
//  - Per-lane affine compose (4 IIR steps), wave scan TRUNCATED to rounds
//    d=1,2,4 (full 2x2+vec) + d=8 (c only): P over 32 steps has norm
//    <=1.5e-5, so d>=16 rounds contribute <1e-9. 22 shuffles total.
//  - Direct coalesced float4 stores from registers (lanes 8..63).

#define T_LEN 88200
#define B_N   48
#define OUT_W 224          // output samples per wave
#define WUP   32           // warm-up samples (lanes 0..7)
#define NCH   394          // ceil(T_LEN / OUT_W)
#define WPB   4            // waves per block (block = 256)

__device__ __forceinline__ float4 zero4() { return make_float4(0.f, 0.f, 0.f, 0.f); }

__device__ __forceinline__ float4 ld_guard(const float* p, int t) {
    // whole-float4 guard: callers guarantee t % 4 == 0
    if (t >= 0 && t + 3 < T_LEN) return *(const float4*)(p + t);
    return zero4();
}

__global__ __launch_bounds__(256, 5) void diffks_kernel(
    const float* __restrict__ y, const float* __restrict__ A_exc,
    const float* __restrict__ A_loop, float* __restrict__ out) {
    const int tid  = threadIdx.x;
    const int widx = tid >> 6;
    const int lane = tid & 63;
    const int w = blockIdx.x * WPB + widx;      // 0..18911 (grid exact)
    const int b = w / NCH;
    const int c = w - b * NCH;
    const int s  = c * OUT_W;
    const int w0 = s - WUP;
    const int t0 = w0 + 4 * lane;               // this lane's first sample

    const float* yb  = y      + (size_t)b * T_LEN;
    const float* aeb = A_exc  + (size_t)b * T_LEN * 6;
    const float* alb = A_loop + (size_t)b * T_LEN * 2;
    float*       ob  = out    + (size_t)b * T_LEN;

    // ---- per-lane direct loads (all 16B-aligned) ----
    const bool valid = (t0 >= 0) && (t0 + 3 < T_LEN);
    float4 yv, ae0, ae1, ae2, ae3, ae4, ae5, al0, al1;
    if (valid) {
        yv = *(const float4*)(yb + t0);
        const float4* pae = (const float4*)(aeb + (size_t)t0 * 6);
        ae0 = pae[0]; ae1 = pae[1]; ae2 = pae[2];
        ae3 = pae[3]; ae4 = pae[4]; ae5 = pae[5];
        const float4* pal = (const float4*)(alb + (size_t)t0 * 2);
        al0 = pal[0]; al1 = pal[1];
    } else {
        yv = ae0 = ae1 = ae2 = ae3 = ae4 = ae5 = al0 = al1 = zero4();
    }

    // ---- y history via shuffles (lanes 0/1 load halo) ----
    float4 ymid, ylo;
    ymid.x = __shfl_up(yv.x, 1, 64); ymid.y = __shfl_up(yv.y, 1, 64);
    ymid.z = __shfl_up(yv.z, 1, 64); ymid.w = __shfl_up(yv.w, 1, 64);
    ylo.x  = __shfl_up(yv.x, 2, 64); ylo.y  = __shfl_up(yv.y, 2, 64);
    ylo.z  = __shfl_up(yv.z, 2, 64); ylo.w  = __shfl_up(yv.w, 2, 64);
    if (lane == 0) ymid = ld_guard(yb, t0 - 4);
    if (lane <= 1) ylo  = ld_guard(yb, t0 - 8);

    float yw[12] = { ylo.x, ylo.y, ylo.z, ylo.w,
                     ymid.x, ymid.y, ymid.z, ymid.w,
                     yv.x, yv.y, yv.z, yv.w };        // yw[i] = y[t0-8+i]
    float aef[24] = { ae0.x, ae0.y, ae0.z, ae0.w, ae1.x, ae1.y, ae1.z, ae1.w,
                      ae2.x, ae2.y, ae2.z, ae2.w, ae3.x, ae3.y, ae3.z, ae3.w,
                      ae4.x, ae4.y, ae4.z, ae4.w, ae5.x, ae5.y, ae5.z, ae5.w };
    float alf[8]  = { al0.x, al0.y, al0.z, al0.w, al1.x, al1.y, al1.z, al1.w };

    // ---- FIR + local affine composition over 4 samples ----
    float xs[4], a1s[4], a2s[4];
    float p00 = 1.f, p01 = 0.f, p10 = 0.f, p11 = 1.f, c0 = 0.f, c1 = 0.f;
#pragma unroll
    for (int j = 0; j < 4; ++j) {
        float xv = yw[8 + j];
#pragma unroll
        for (int k = 1; k <= 6; ++k)
            xv = fmaf(aef[j * 6 + (k - 1)], yw[8 + j - k], xv);
        xs[j] = xv;
        const float a1 = alf[j * 2], a2 = alf[j * 2 + 1];
        a1s[j] = a1; a2s[j] = a2;
        // P <- M_t * P ; c <- M_t * c + b_t   (M_t = [[-a1,-a2],[1,0]])
        const float n00 = fmaf(-a1, p00, -a2 * p10);
        const float n01 = fmaf(-a1, p01, -a2 * p11);
        p10 = p00; p11 = p01; p00 = n00; p01 = n01;
        const float nc0 = fmaf(-a1, c0, fmaf(-a2, c1, xv));
        c1 = c0; c0 = nc0;
    }

    // ---- truncated wave scan: d=1,2,4 full; d=8 c-only ----
#pragma unroll
    for (int d = 1; d <= 4; d <<= 1) {
        const float q00 = __shfl_up(p00, d, 64), q01 = __shfl_up(p01, d, 64);
        const float q10 = __shfl_up(p10, d, 64), q11 = __shfl_up(p11, d, 64);
        const float qc0 = __shfl_up(c0, d, 64),  qc1 = __shfl_up(c1, d, 64);
        if (lane >= d) {
            const float m00 = fmaf(p00, q00, p01 * q10);
            const float m01 = fmaf(p00, q01, p01 * q11);
            const float m10 = fmaf(p10, q00, p11 * q10);
            const float m11 = fmaf(p10, q01, p11 * q11);
            const float nc0 = fmaf(p00, qc0, fmaf(p01, qc1, c0));
            const float nc1 = fmaf(p10, qc0, fmaf(p11, qc1, c1));
            p00 = m00; p01 = m01; p10 = m10; p11 = m11; c0 = nc0; c1 = nc1;
        }
    }
    {   // d = 8: P spans <=32 steps (norm <=1.5e-5) -> only c matters
        const float qc0 = __shfl_up(c0, 8, 64), qc1 = __shfl_up(c1, 8, 64);
        if (lane >= 8) {
            const float nc0 = fmaf(p00, qc0, fmaf(p01, qc1, c0));
            const float nc1 = fmaf(p10, qc0, fmaf(p11, qc1, c1));
            c0 = nc0; c1 = nc1;
        }
    }

    // ---- exclusive prefix = incoming state; replay 4 samples ----
    float y1 = __shfl_up(c0, 1, 64);
    float y2 = __shfl_up(c1, 1, 64);
    if (lane == 0) { y1 = 0.f; y2 = 0.f; }
    float ov[4];
#pragma unroll
    for (int j = 0; j < 4; ++j) {
        const float yt = fmaf(-a1s[j], y1, fmaf(-a2s[j], y2, xs[j]));
        y2 = y1; y1 = yt;
        ov[j] = yt;
    }

    // ---- direct coalesced store (lanes 8..63 = output region) ----
    if (lane >= 8 && t0 < T_LEN)
        *(float4*)(ob + t0) = make_float4(ov[0], ov[1], ov[2], ov[3]);
}

extern "C" void kernel_launch(void* const* d_in, const int* in_sizes, int n_in,
                              void* d_out, int out_size, void* d_ws, size_t ws_size,
                              hipStream_t stream) {
    const float* y      = (const float*)d_in[0];
    const float* A_exc  = (const float*)d_in[1];
    const float* A_loop = (const float*)d_in[2];
    float* out = (float*)d_out;

    const int waves = B_N * NCH;          // 48 * 394 = 18912
    const int grid  = waves / WPB;        // 4728 blocks of 4 waves
    diffks_kernel<<<grid, 256, 0, stream>>>(y, A_exc, A_loop, out);
}